// Round 2
// baseline (306.068 us; speedup 1.0000x reference)
//
#include <hip/hip_runtime.h>
#include <stdint.h>

// ---------------------------------------------------------------------------
// GAT layer, dtype-adaptive (probed: fp32 inputs, int32 edge_index, bf16 out).
//   fused:  h = x@W via split-f16 MFMA (x,W -> f16 hi+lo, 3 MFMA combos,
//           fp32 accum == fp32-grade numerics), attn dots in epilogue,
//           h->bf16                                    [slots 8-15 of 16]
//           XCD-partitioned slotted-CSR scatter: dst space split 8 ways,
//           group g on XCD g (bid%8 heuristic), dst-only prescan + filtered
//           src load/atomic/store -> cnt/esrc lines single-XCD resident
//                                                      [slots 0-7  of 16]
//   aggregate: one wave/node, self-loop at lane 0, butterfly softmax denom,
//              dword gathers (2 ch/lane), 4 in flight.     (unchanged)
// ---------------------------------------------------------------------------

#define SLOT 64
#define CNTS 16   // counter stride in ints = one 64B line per node

typedef __attribute__((ext_vector_type(8))) _Float16 h8;
typedef __attribute__((ext_vector_type(4))) float    f4x;

__device__ __forceinline__ float b2f(unsigned short u) {
    union { unsigned int i; float f; } v; v.i = ((unsigned int)u) << 16; return v.f;
}
__device__ __forceinline__ unsigned short f2b(float f) {
    union { float f; unsigned int i; } v; v.f = f;
    unsigned int i = v.i;
    unsigned int r = (i + 0x7FFFu + ((i >> 16) & 1u)) >> 16;  // RNE
    return (unsigned short)r;
}
__device__ __forceinline__ unsigned short f2h(float f) {
    union { _Float16 h; unsigned short u; } v; v.h = (_Float16)f; return v.u;
}
__device__ __forceinline__ float h2f(unsigned short u) {
    union { _Float16 h; unsigned short u; } v; v.u = u; return (float)v.h;
}

// --- 0. dtype probes --------------------------------------------------------
__global__ void k_detect(const int* __restrict__ eidx, const unsigned int* __restrict__ xw,
                         int* flags) {
    __shared__ int nz, bf;
    if (threadIdx.x == 0) { nz = 0; bf = 0; }
    __syncthreads();
    int bad = 0;
    for (int i = threadIdx.x; i < 1024; i += 256)
        if (eidx[2 * i + 1] != 0) bad = 1;
    if (bad) atomicOr(&nz, 1);
    int hits = 0;
    for (int i = threadIdx.x; i < 4096; i += 256) {
        unsigned int e = (xw[i] >> 7) & 0xFFu;
        if (e >= 0x60u && e < 0xA0u) ++hits;
    }
    atomicAdd(&bf, hits);
    __syncthreads();
    if (threadIdx.x == 0) {
        flags[0] = (nz == 0) ? 1 : 0;   // 1 => int64 edge_index
        flags[1] = (bf > 3072) ? 1 : 0; // 1 => bf16 float tensors
    }
}

__device__ __forceinline__ int edge_at(const int* idx32, const long long* idx64,
                                       int is64, long long pos) {
    return is64 ? (int)idx64[pos] : idx32[pos];
}

// --- 0b. W^T hi/lo f16 + att/bias fp32 -> ws --------------------------------
__global__ void k_prep(const void* __restrict__ Wv, const void* __restrict__ asv,
                       const void* __restrict__ adv, const void* __restrict__ bv,
                       const int* __restrict__ flags,
                       _Float16* __restrict__ Wth, _Float16* __restrict__ Wtl,
                       float* __restrict__ attf /*256*/, float* __restrict__ biasf /*128*/) {
    int isbf = flags[1];
    int tid = blockIdx.x * 256 + threadIdx.x;
    for (int i = tid; i < 16384; i += gridDim.x * 256) {
        int col = i >> 7, k = i & 127;            // Wt[col][k] = W[k][col]
        float w = isbf ? b2f(((const unsigned short*)Wv)[k * 128 + col])
                       : ((const float*)Wv)[k * 128 + col];
        unsigned short hi = f2h(w);
        unsigned short lo = f2h(w - h2f(hi));
        ((unsigned short*)Wth)[i] = hi;
        ((unsigned short*)Wtl)[i] = lo;
    }
    if (blockIdx.x == 0) {
        for (int i = threadIdx.x; i < 128; i += 256) {
            attf[i]       = isbf ? b2f(((const unsigned short*)asv)[i]) : ((const float*)asv)[i];
            attf[128 + i] = isbf ? b2f(((const unsigned short*)adv)[i]) : ((const float*)adv)[i];
            biasf[i]      = isbf ? b2f(((const unsigned short*)bv)[i]) : ((const float*)bv)[i];
        }
    }
}

// --- 1. fused MFMA GEMM (slots 8-15) + partitioned scatter (slots 0-7) ------
__global__ __launch_bounds__(256) void k_gemm_scatter(
    const void* __restrict__ xv,
    const _Float16* __restrict__ Wth, const _Float16* __restrict__ Wtl,
    const float* __restrict__ attf, const int* __restrict__ flags,
    unsigned short* __restrict__ hbf, float* __restrict__ asf,
    float* __restrict__ adf, int N,
    const int* __restrict__ idx32, const long long* __restrict__ idx64,
    int* __restrict__ cnt, int* __restrict__ esrc, int E, int Gg, int CH) {
    __shared__ unsigned short xsh[64 * 128];   // x hi-plane, f16, XOR-swizzled
    __shared__ unsigned short xsl[64 * 128];   // x lo-plane, f16, XOR-swizzled
    int cell = blockIdx.x >> 4;
    int slot = blockIdx.x & 15;
    int tid = threadIdx.x;

    if (slot < 8) {                            // ---- partitioned scatter ----
        int gpart = slot;                      // dst slice == XCD (bid%8 heuristic)
        long long e0 = (long long)cell * CH;
        if (e0 >= E) return;
        long long e1 = e0 + CH; if (e1 > E) e1 = E;
        int is64 = flags[0];
        int NS = (N + 7) >> 3;
        unsigned lo = (unsigned)(gpart * NS);
        bool al = ((E & 3) == 0) && !is64;     // int4-able dst/src arrays

        for (long long base = e0 + tid * 4; base < e1; base += 1024) {
            if (base + 3 < e1) {
                int d0, d1, d2, d3;
                if (is64) {
                    d0 = (int)idx64[E + base];     d1 = (int)idx64[E + base + 1];
                    d2 = (int)idx64[E + base + 2]; d3 = (int)idx64[E + base + 3];
                } else if (al) {
                    int4 dv = *(const int4*)(idx32 + E + base);
                    d0 = dv.x; d1 = dv.y; d2 = dv.z; d3 = dv.w;
                } else {
                    d0 = idx32[E + base];     d1 = idx32[E + base + 1];
                    d2 = idx32[E + base + 2]; d3 = idx32[E + base + 3];
                }
                if ((unsigned)(d0 - lo) < (unsigned)NS) {
                    int s0 = is64 ? (int)idx64[base] : idx32[base];
                    int p0 = atomicAdd(&cnt[(size_t)d0 * CNTS], 1);
                    if (p0 < SLOT) esrc[(size_t)d0 * SLOT + p0] = s0;
                }
                if ((unsigned)(d1 - lo) < (unsigned)NS) {
                    int s1 = is64 ? (int)idx64[base + 1] : idx32[base + 1];
                    int p1 = atomicAdd(&cnt[(size_t)d1 * CNTS], 1);
                    if (p1 < SLOT) esrc[(size_t)d1 * SLOT + p1] = s1;
                }
                if ((unsigned)(d2 - lo) < (unsigned)NS) {
                    int s2 = is64 ? (int)idx64[base + 2] : idx32[base + 2];
                    int p2 = atomicAdd(&cnt[(size_t)d2 * CNTS], 1);
                    if (p2 < SLOT) esrc[(size_t)d2 * SLOT + p2] = s2;
                }
                if ((unsigned)(d3 - lo) < (unsigned)NS) {
                    int s3 = is64 ? (int)idx64[base + 3] : idx32[base + 3];
                    int p3 = atomicAdd(&cnt[(size_t)d3 * CNTS], 1);
                    if (p3 < SLOT) esrc[(size_t)d3 * SLOT + p3] = s3;
                }
            } else {
                for (long long e = base; e < e1; ++e) {
                    int d = edge_at(idx32, idx64, is64, (long long)E + e);
                    if ((unsigned)(d - lo) < (unsigned)NS) {
                        int s = edge_at(idx32, idx64, is64, e);
                        int p = atomicAdd(&cnt[(size_t)d * CNTS], 1);
                        if (p < SLOT) esrc[(size_t)d * SLOT + p] = s;
                    }
                }
            }
        }
        return;
    }

    // ---- MFMA GEMM ----
    int rb = cell * 8 + (slot - 8);
    if (rb >= Gg) return;
    int r0 = rb * 64;
    int isbf = flags[1];
    int w = tid >> 6;            // wave id = head id (owns cols [32w, 32w+32))
    int lane = tid & 63;
    int li = lane & 15;          // fragment row/col index
    int g  = lane >> 4;          // k-group
    int c0 = w * 32;

    // B fragments (W^T hi/lo) -> registers, once per block. Independent of LDS,
    // issued before staging so latency hides under the x stream.
    h8 Bh[2][4], Bl[2][4];
#pragma unroll
    for (int t = 0; t < 2; ++t)
#pragma unroll
        for (int s = 0; s < 4; ++s) {
            size_t o = (size_t)(c0 + 16 * t + li) * 128 + 32 * s + 8 * g;
            Bh[t][s] = *(const h8*)(Wth + o);
            Bl[t][s] = *(const h8*)(Wtl + o);
        }

    // Stage x rows r0..r0+63: fp32 (or bf16) -> f16 hi/lo planes, swizzled.
#pragma unroll
    for (int it = 0; it < 4; ++it) {
        int idx = it * 2048 + tid * 8;         // 8 elements per thread per iter
        int r = idx >> 7, k = idx & 127;
        int gr = r0 + r; if (gr >= N) gr = N - 1;
        float v[8];
        if (isbf) {
            uint4 raw = *(const uint4*)((const unsigned short*)xv + (size_t)gr * 128 + k);
            v[0] = b2f((unsigned short)(raw.x & 0xFFFFu)); v[1] = b2f((unsigned short)(raw.x >> 16));
            v[2] = b2f((unsigned short)(raw.y & 0xFFFFu)); v[3] = b2f((unsigned short)(raw.y >> 16));
            v[4] = b2f((unsigned short)(raw.z & 0xFFFFu)); v[5] = b2f((unsigned short)(raw.z >> 16));
            v[6] = b2f((unsigned short)(raw.w & 0xFFFFu)); v[7] = b2f((unsigned short)(raw.w >> 16));
        } else {
            const float* xf = (const float*)xv;
            float4 a = *(const float4*)(xf + (size_t)gr * 128 + k);
            float4 b = *(const float4*)(xf + (size_t)gr * 128 + k + 4);
            v[0] = a.x; v[1] = a.y; v[2] = a.z; v[3] = a.w;
            v[4] = b.x; v[5] = b.y; v[6] = b.z; v[7] = b.w;
        }
        uint4 PH, PL;
        unsigned int ph[4], pl[4];
#pragma unroll
        for (int jj = 0; jj < 4; ++jj) {
            unsigned short h0 = f2h(v[2 * jj]), h1 = f2h(v[2 * jj + 1]);
            unsigned short l0 = f2h(v[2 * jj] - h2f(h0));
            unsigned short l1 = f2h(v[2 * jj + 1] - h2f(h1));
            ph[jj] = (unsigned int)h0 | ((unsigned int)h1 << 16);
            pl[jj] = (unsigned int)l0 | ((unsigned int)l1 << 16);
        }
        PH.x = ph[0]; PH.y = ph[1]; PH.z = ph[2]; PH.w = ph[3];
        PL.x = pl[0]; PL.y = pl[1]; PL.z = pl[2]; PL.w = pl[3];
        int off = r * 256 + ((2 * k) ^ ((r & 7) << 4));   // 16B-slot XOR swizzle
        *(uint4*)((char*)xsh + off) = PH;
        *(uint4*)((char*)xsl + off) = PL;
    }
    __syncthreads();

    // Main loop: acc[m][t] over 4 m-tiles x 2 n-tiles, K=128 in 4 steps of 32.
    // x*W = xh*Wh + xl*Wh + xh*Wl  (xl*Wl ~2^-22 rel, dropped) -> fp32-grade.
    f4x acc[4][2];
#pragma unroll
    for (int m = 0; m < 4; ++m)
#pragma unroll
        for (int t = 0; t < 2; ++t) acc[m][t] = (f4x){0.f, 0.f, 0.f, 0.f};

#pragma unroll
    for (int s = 0; s < 4; ++s) {
#pragma unroll
        for (int m = 0; m < 4; ++m) {
            int row = 16 * m + li;
            int kb = (32 * s + 8 * g) * 2;
            int off = row * 256 + (kb ^ ((row & 7) << 4));
            h8 ah = *(const h8*)((const char*)xsh + off);
            h8 al = *(const h8*)((const char*)xsl + off);
#pragma unroll
            for (int t = 0; t < 2; ++t) {
                acc[m][t] = __builtin_amdgcn_mfma_f32_16x16x32_f16(ah, Bh[t][s], acc[m][t], 0, 0, 0);
                acc[m][t] = __builtin_amdgcn_mfma_f32_16x16x32_f16(al, Bh[t][s], acc[m][t], 0, 0, 0);
                acc[m][t] = __builtin_amdgcn_mfma_f32_16x16x32_f16(ah, Bl[t][s], acc[m][t], 0, 0, 0);
            }
        }
    }

    // Epilogue 1: attn dots from fp32 acc. C/D: col = li, row = 4*g + reg.
    float at_s0 = attf[c0 + li],       at_s1 = attf[c0 + 16 + li];
    float at_d0 = attf[128 + c0 + li], at_d1 = attf[128 + c0 + 16 + li];
#pragma unroll
    for (int m = 0; m < 4; ++m) {
        float s1v[4], s2v[4];
#pragma unroll
        for (int j = 0; j < 4; ++j) {
            s1v[j] = acc[m][0][j] * at_s0 + acc[m][1][j] * at_s1;
            s2v[j] = acc[m][0][j] * at_d0 + acc[m][1][j] * at_d1;
        }
#pragma unroll
        for (int j = 0; j < 4; ++j) {
#pragma unroll
            for (int msk = 1; msk < 16; msk <<= 1) {
                s1v[j] += __shfl_xor(s1v[j], msk);
                s2v[j] += __shfl_xor(s2v[j], msk);
            }
        }
        if (li == 0) {
#pragma unroll
            for (int j = 0; j < 4; ++j) {
                int gr = r0 + 16 * m + 4 * g + j;
                if (gr < N) {
                    asf[(size_t)gr * 4 + w] = s1v[j];
                    adf[(size_t)gr * 4 + w] = s2v[j];
                }
            }
        }
    }

    // Epilogue 2: h -> bf16 via LDS (reuse hi-plane) for coalesced store.
    __syncthreads();
#pragma unroll
    for (int m = 0; m < 4; ++m)
#pragma unroll
        for (int t = 0; t < 2; ++t)
#pragma unroll
            for (int j = 0; j < 4; ++j)
                xsh[(16 * m + 4 * g + j) * 128 + c0 + 16 * t + li] = f2b(acc[m][t][j]);
    __syncthreads();
#pragma unroll
    for (int it = 0; it < 4; ++it) {
        int u = it * 2048 + tid * 8;
        int r = u >> 7, k = u & 127;
        int gr = r0 + r;
        if (gr < N)
            *(uint4*)(hbf + (size_t)gr * 128 + k) = *(const uint4*)(xsh + u);
    }
}

// --- 2. aggregate: one wave per node; self-loop = lane 0 (unchanged) --------
__global__ __launch_bounds__(256) void k_aggregate(
    const unsigned short* __restrict__ hbf,
    const float* __restrict__ asf, const float* __restrict__ adf,
    const int* __restrict__ cnt, const int* __restrict__ esrc,
    const int* __restrict__ idx32, const long long* __restrict__ idx64,
    const float* __restrict__ biasf, const int* __restrict__ flags,
    void* __restrict__ outv, int N, int E) {
    __shared__ float p_sh_all[4][SLOT * 4];
    __shared__ int   s_sh_all[4][SLOT];
    int wid = threadIdx.x >> 6;
    int lane = threadIdx.x & 63;
    int n = blockIdx.x * 4 + wid;
    if (n >= N) n = N - 1;                     // tail waves redo a node (benign)
    float* p_sh = p_sh_all[wid];
    int*   s_sh = s_sh_all[wid];
    int head = lane >> 4;

    int deg = cnt[(size_t)n * CNTS];           // edges, excl. self-loop
    float4 adv = *(const float4*)(adf + (size_t)n * 4);
    bool fb = (deg > SLOT - 1);                // total deg+1 must fit in 64

    float p0 = 0.f, p1 = 0.f, p2 = 0.f, p3 = 0.f;
    if (!fb && lane <= deg) {                  // phase 1: one item per lane
        int s = (lane == 0) ? n : esrc[(size_t)n * SLOT + lane - 1];
        float4 av = *(const float4*)(asf + (size_t)s * 4);
        float e0 = av.x + adv.x; e0 = fmaxf(e0, 0.2f * e0); p0 = __expf(e0);
        float e1 = av.y + adv.y; e1 = fmaxf(e1, 0.2f * e1); p1 = __expf(e1);
        float e2 = av.z + adv.z; e2 = fmaxf(e2, 0.2f * e2); p2 = __expf(e2);
        float e3 = av.w + adv.w; e3 = fmaxf(e3, 0.2f * e3); p3 = __expf(e3);
        s_sh[lane] = s;
        p_sh[lane * 4 + 0] = p0; p_sh[lane * 4 + 1] = p1;
        p_sh[lane * 4 + 2] = p2; p_sh[lane * 4 + 3] = p3;
    }
    __syncthreads();

    float b0 = biasf[2 * lane], b1 = biasf[2 * lane + 1];
    float a0 = 0.f, a1 = 0.f, invh;

    if (!fb) {
        float ps0 = p0, ps1 = p1, ps2 = p2, ps3 = p3;
#pragma unroll
        for (int m = 1; m < 64; m <<= 1) {     // 64-lane butterfly
            ps0 += __shfl_xor(ps0, m);
            ps1 += __shfl_xor(ps1, m);
            ps2 += __shfl_xor(ps2, m);
            ps3 += __shfl_xor(ps3, m);
        }
        float den = head == 0 ? ps0 : head == 1 ? ps1 : head == 2 ? ps2 : ps3;
        invh = 1.0f / (den + 1e-16f);

        int tot = deg + 1;
        int i = 0;
        for (; i + 3 < tot; i += 4) {          // 4 row-gathers in flight
            int s0 = s_sh[i], s1 = s_sh[i + 1], s2 = s_sh[i + 2], s3 = s_sh[i + 3];
            float q0 = p_sh[i * 4 + head],       q1 = p_sh[(i + 1) * 4 + head];
            float q2 = p_sh[(i + 2) * 4 + head], q3 = p_sh[(i + 3) * 4 + head];
            unsigned int v0 = *(const unsigned int*)(hbf + (size_t)s0 * 128 + 2 * lane);
            unsigned int v1 = *(const unsigned int*)(hbf + (size_t)s1 * 128 + 2 * lane);
            unsigned int v2 = *(const unsigned int*)(hbf + (size_t)s2 * 128 + 2 * lane);
            unsigned int v3 = *(const unsigned int*)(hbf + (size_t)s3 * 128 + 2 * lane);
            a0 += q0 * b2f((unsigned short)v0) + q1 * b2f((unsigned short)v1)
                + q2 * b2f((unsigned short)v2) + q3 * b2f((unsigned short)v3);
            a1 += q0 * b2f((unsigned short)(v0 >> 16)) + q1 * b2f((unsigned short)(v1 >> 16))
                + q2 * b2f((unsigned short)(v2 >> 16)) + q3 * b2f((unsigned short)(v3 >> 16));
        }
        for (; i < tot; ++i) {
            int s0 = s_sh[i];
            float q0 = p_sh[i * 4 + head];
            unsigned int v0 = *(const unsigned int*)(hbf + (size_t)s0 * 128 + 2 * lane);
            a0 += q0 * b2f((unsigned short)v0);
            a1 += q0 * b2f((unsigned short)(v0 >> 16));
        }
    } else {
        // parachute: degree >= SLOT (statistically never). Full edge rescan.
        int is64 = flags[0];
        float adh = head == 0 ? adv.x : head == 1 ? adv.y : head == 2 ? adv.z : adv.w;
        float den = 0.f;
        {   // self-loop
            float ev = asf[(size_t)n * 4 + head] + adh; ev = fmaxf(ev, 0.2f * ev);
            float p = __expf(ev);
            unsigned int v = *(const unsigned int*)(hbf + (size_t)n * 128 + 2 * lane);
            den += p;
            a0 += p * b2f((unsigned short)v);
            a1 += p * b2f((unsigned short)(v >> 16));
        }
        for (int e = 0; e < E; ++e) {
            int d = edge_at(idx32, idx64, is64, (long long)E + e);
            if (d == n) {
                int s = edge_at(idx32, idx64, is64, e);
                float ev = asf[(size_t)s * 4 + head] + adh; ev = fmaxf(ev, 0.2f * ev);
                float p = __expf(ev);
                unsigned int v = *(const unsigned int*)(hbf + (size_t)s * 128 + 2 * lane);
                den += p;
                a0 += p * b2f((unsigned short)v);
                a1 += p * b2f((unsigned short)(v >> 16));
            }
        }
        invh = 1.0f / (den + 1e-16f);
    }

    a0 = a0 * invh + b0;
    a1 = a1 * invh + b1;
    if (flags[1]) {
        unsigned int pk = (unsigned int)f2b(a0) | ((unsigned int)f2b(a1) << 16);
        ((unsigned int*)outv)[(size_t)n * 64 + lane] = pk;
    } else {
        float2 f2; f2.x = a0; f2.y = a1;
        *(float2*)((float*)outv + (size_t)n * 128 + 2 * lane) = f2;
    }
}

// ---------------------------------------------------------------------------
extern "C" void kernel_launch(void* const* d_in, const int* in_sizes, int n_in,
                              void* d_out, int out_size, void* d_ws, size_t ws_size,
                              hipStream_t stream) {
    const void*      xv    = d_in[0];
    const int*       idx32 = (const int*)d_in[1];
    const long long* idx64 = (const long long*)d_in[1];

    int N = in_sizes[0] / 128;
    int E = in_sizes[1] / 2;

    char* ws = (char*)d_ws;
    size_t o = 0;
    auto alloc = [&](size_t bytes) {
        size_t r = o; o += (bytes + 255) & ~(size_t)255; return r;
    };
    unsigned short* hbf = (unsigned short*)(ws + alloc((size_t)N * 128 * 2));
    _Float16* Wth = (_Float16*)(ws + alloc(16384 * 2));
    _Float16* Wtl = (_Float16*)(ws + alloc(16384 * 2));
    float* attf  = (float*)(ws + alloc(256 * 4));
    float* biasf = (float*)(ws + alloc(128 * 4));
    float* asf   = (float*)(ws + alloc((size_t)N * 4 * 4));
    float* adf   = (float*)(ws + alloc((size_t)N * 4 * 4));
    int* cnt     = (int*)(ws + alloc((size_t)N * CNTS * 4));
    int* flags   = (int*)(ws + alloc(256));
    int* esrc    = (int*)(ws + alloc((size_t)N * SLOT * 4));

    int Gg = (N + 63) / 64;                    // gemm tiles (64 rows each)
    int cells = (Gg + 7) / 8;                  // grid cells of 16 blocks
    long long ch = ((long long)E + cells - 1) / cells;
    int CH = (int)((ch + 1023) & ~1023LL);     // edge chunk per scatter block
    if (CH < 1024) CH = 1024;
    int NB = 16 * cells;

    k_detect<<<1, 256, 0, stream>>>(idx32, (const unsigned int*)xv, flags);
    k_prep<<<16, 256, 0, stream>>>(d_in[2], d_in[3], d_in[4], d_in[5], flags, Wth, Wtl, attf, biasf);
    hipMemsetAsync(cnt, 0, (size_t)N * CNTS * 4, stream);
    k_gemm_scatter<<<NB, 256, 0, stream>>>(xv, Wth, Wtl, attf, flags, hbf, asf, adf, N,
                                           idx32, idx64, cnt, esrc, E, Gg, CH);
    k_aggregate<<<(N + 3) / 4, 256, 0, stream>>>(hbf, asf, adf, cnt, esrc, idx32, idx64,
                                                 biasf, flags, d_out, N, E);
}

// Round 3
// 271.684 us; speedup vs baseline: 1.1266x; 1.1266x over previous
//
#include <hip/hip_runtime.h>
#include <stdint.h>

// ---------------------------------------------------------------------------
// GAT layer, dtype-adaptive (probed: fp32 inputs, int32 edge_index, bf16 out).
//   fused:  h = x@W via split-f16 MFMA (fp32-grade), attn dots in epilogue
//           [blocks SB..SB+Gg)  -- unchanged from R1]
//           bucketed scatter: 64-node buckets, per-chunk LDS histogram +
//           ONE device atomic per (chunk,bucket) run-claim (~10x fewer
//           device atomics than per-edge), packed (src|dlow) entries
//           [blocks 0..SB)]
//   demux:  one block per bucket: bucket entries -> exact cnt/esrc CSR via
//           LDS atomics, coalesced int4 row writes. Aggregate unchanged.
//   aggregate: one wave/node, self-loop lane 0, butterfly softmax denom.
// ---------------------------------------------------------------------------

#define SLOT 64
#define CNTS 16    // counter stride in ints = one 64B line per node
#define BCAP 1536  // bucket capacity (entries); avg fill 1024, ~16 sigma slack
#define MAXB 2048  // max buckets supported by LDS histogram (N <= 131072)
#define KCH  16384 // edges per scatter chunk

typedef __attribute__((ext_vector_type(8))) _Float16 h8;
typedef __attribute__((ext_vector_type(4))) float    f4x;

__device__ __forceinline__ float b2f(unsigned short u) {
    union { unsigned int i; float f; } v; v.i = ((unsigned int)u) << 16; return v.f;
}
__device__ __forceinline__ unsigned short f2b(float f) {
    union { float f; unsigned int i; } v; v.f = f;
    unsigned int i = v.i;
    unsigned int r = (i + 0x7FFFu + ((i >> 16) & 1u)) >> 16;  // RNE
    return (unsigned short)r;
}
__device__ __forceinline__ unsigned short f2h(float f) {
    union { _Float16 h; unsigned short u; } v; v.h = (_Float16)f; return v.u;
}
__device__ __forceinline__ float h2f(unsigned short u) {
    union { _Float16 h; unsigned short u; } v; v.u = u; return (float)v.h;
}

// --- 0. dtype probes --------------------------------------------------------
__global__ void k_detect(const int* __restrict__ eidx, const unsigned int* __restrict__ xw,
                         int* flags) {
    __shared__ int nz, bf;
    if (threadIdx.x == 0) { nz = 0; bf = 0; }
    __syncthreads();
    int bad = 0;
    for (int i = threadIdx.x; i < 1024; i += 256)
        if (eidx[2 * i + 1] != 0) bad = 1;
    if (bad) atomicOr(&nz, 1);
    int hits = 0;
    for (int i = threadIdx.x; i < 4096; i += 256) {
        unsigned int e = (xw[i] >> 7) & 0xFFu;
        if (e >= 0x60u && e < 0xA0u) ++hits;
    }
    atomicAdd(&bf, hits);
    __syncthreads();
    if (threadIdx.x == 0) {
        flags[0] = (nz == 0) ? 1 : 0;   // 1 => int64 edge_index
        flags[1] = (bf > 3072) ? 1 : 0; // 1 => bf16 float tensors
    }
}

__device__ __forceinline__ int edge_at(const int* idx32, const long long* idx64,
                                       int is64, long long pos) {
    return is64 ? (int)idx64[pos] : idx32[pos];
}

// --- 0b. W^T hi/lo f16 + att/bias fp32 -> ws --------------------------------
__global__ void k_prep(const void* __restrict__ Wv, const void* __restrict__ asv,
                       const void* __restrict__ adv, const void* __restrict__ bv,
                       const int* __restrict__ flags,
                       _Float16* __restrict__ Wth, _Float16* __restrict__ Wtl,
                       float* __restrict__ attf /*256*/, float* __restrict__ biasf /*128*/) {
    int isbf = flags[1];
    int tid = blockIdx.x * 256 + threadIdx.x;
    for (int i = tid; i < 16384; i += gridDim.x * 256) {
        int col = i >> 7, k = i & 127;            // Wt[col][k] = W[k][col]
        float w = isbf ? b2f(((const unsigned short*)Wv)[k * 128 + col])
                       : ((const float*)Wv)[k * 128 + col];
        unsigned short hi = f2h(w);
        unsigned short lo = f2h(w - h2f(hi));
        ((unsigned short*)Wth)[i] = hi;
        ((unsigned short*)Wtl)[i] = lo;
    }
    if (blockIdx.x == 0) {
        for (int i = threadIdx.x; i < 128; i += 256) {
            attf[i]       = isbf ? b2f(((const unsigned short*)asv)[i]) : ((const float*)asv)[i];
            attf[128 + i] = isbf ? b2f(((const unsigned short*)adv)[i]) : ((const float*)adv)[i];
            biasf[i]      = isbf ? b2f(((const unsigned short*)bv)[i]) : ((const float*)bv)[i];
        }
    }
}

// --- 1. fused MFMA GEMM (blocks >= SB) + bucketed scatter (blocks < SB) -----
__global__ __launch_bounds__(256) void k_gemm_scatter(
    const void* __restrict__ xv,
    const _Float16* __restrict__ Wth, const _Float16* __restrict__ Wtl,
    const float* __restrict__ attf, const int* __restrict__ flags,
    unsigned short* __restrict__ hbf, float* __restrict__ asf,
    float* __restrict__ adf, int N,
    const int* __restrict__ idx32, const long long* __restrict__ idx64,
    int* __restrict__ bcnt, unsigned* __restrict__ bdat,
    int* __restrict__ cnt, int* __restrict__ esrc,
    int E, int Gg, int SB) {
    __shared__ unsigned short xsh[64 * 128];   // x hi-plane / scatter histogram
    __shared__ unsigned short xsl[64 * 128];   // x lo-plane
    int tid = threadIdx.x;
    int bid = blockIdx.x;

    if (bid < SB) {                            // ---- bucketed scatter ----
        int is64 = flags[0];
        int NBK = (N + 63) >> 6;
        long long e0 = (long long)bid * KCH;
        long long e1 = e0 + KCH; if (e1 > E) e1 = E;
        if (e0 >= E) return;

        if (NBK <= MAXB) {
            int* hist = (int*)xsh;             // 8KB alias (role-exclusive)
            for (int i = tid; i < NBK; i += 256) hist[i] = 0;
            __syncthreads();
            // pass 1: chunk histogram over buckets (LDS atomics)
            for (long long e = e0 + tid; e < e1; e += 256) {
                int d = is64 ? (int)idx64[(long long)E + e] : idx32[E + e];
                atomicAdd(&hist[d >> 6], 1);
            }
            __syncthreads();
            // claim: one device atomic per non-empty bucket
            for (int b = tid; b < NBK; b += 256) {
                int c = hist[b];
                hist[b] = (c > 0) ? atomicAdd(&bcnt[b], c) : 0;
            }
            __syncthreads();
            // pass 2: place entries at LDS-cursor offsets
            for (long long e = e0 + tid; e < e1; e += 256) {
                int d, s;
                if (is64) {
                    d = (int)idx64[(long long)E + e]; s = (int)idx64[e];
                } else {
                    d = idx32[E + e]; s = idx32[e];
                }
                int b = d >> 6;
                int p = atomicAdd(&hist[b], 1);
                if (p < BCAP)
                    bdat[(size_t)b * BCAP + p] = (unsigned)s | ((unsigned)(d & 63) << 26);
            }
        } else {
            // legacy per-edge path (host memsets cnt, skips demux)
            for (long long e = e0 + tid; e < e1; e += 256) {
                int d = edge_at(idx32, idx64, is64, (long long)E + e);
                int s = edge_at(idx32, idx64, is64, e);
                int p = atomicAdd(&cnt[(size_t)d * CNTS], 1);
                if (p < SLOT) esrc[(size_t)d * SLOT + p] = s;
            }
        }
        return;
    }

    // ---- MFMA GEMM (unchanged from R1) ----
    int rb = bid - SB;
    if (rb >= Gg) return;
    int r0 = rb * 64;
    int isbf = flags[1];
    int w = tid >> 6;            // wave id = head id (owns cols [32w, 32w+32))
    int lane = tid & 63;
    int li = lane & 15;          // fragment row/col index
    int g  = lane >> 4;          // k-group
    int c0 = w * 32;

    h8 Bh[2][4], Bl[2][4];
#pragma unroll
    for (int t = 0; t < 2; ++t)
#pragma unroll
        for (int s = 0; s < 4; ++s) {
            size_t o = (size_t)(c0 + 16 * t + li) * 128 + 32 * s + 8 * g;
            Bh[t][s] = *(const h8*)(Wth + o);
            Bl[t][s] = *(const h8*)(Wtl + o);
        }

#pragma unroll
    for (int it = 0; it < 4; ++it) {
        int idx = it * 2048 + tid * 8;         // 8 elements per thread per iter
        int r = idx >> 7, k = idx & 127;
        int gr = r0 + r; if (gr >= N) gr = N - 1;
        float v[8];
        if (isbf) {
            uint4 raw = *(const uint4*)((const unsigned short*)xv + (size_t)gr * 128 + k);
            v[0] = b2f((unsigned short)(raw.x & 0xFFFFu)); v[1] = b2f((unsigned short)(raw.x >> 16));
            v[2] = b2f((unsigned short)(raw.y & 0xFFFFu)); v[3] = b2f((unsigned short)(raw.y >> 16));
            v[4] = b2f((unsigned short)(raw.z & 0xFFFFu)); v[5] = b2f((unsigned short)(raw.z >> 16));
            v[6] = b2f((unsigned short)(raw.w & 0xFFFFu)); v[7] = b2f((unsigned short)(raw.w >> 16));
        } else {
            const float* xf = (const float*)xv;
            float4 a = *(const float4*)(xf + (size_t)gr * 128 + k);
            float4 b = *(const float4*)(xf + (size_t)gr * 128 + k + 4);
            v[0] = a.x; v[1] = a.y; v[2] = a.z; v[3] = a.w;
            v[4] = b.x; v[5] = b.y; v[6] = b.z; v[7] = b.w;
        }
        uint4 PH, PL;
        unsigned int ph[4], pl[4];
#pragma unroll
        for (int jj = 0; jj < 4; ++jj) {
            unsigned short h0 = f2h(v[2 * jj]), h1 = f2h(v[2 * jj + 1]);
            unsigned short l0 = f2h(v[2 * jj] - h2f(h0));
            unsigned short l1 = f2h(v[2 * jj + 1] - h2f(h1));
            ph[jj] = (unsigned int)h0 | ((unsigned int)h1 << 16);
            pl[jj] = (unsigned int)l0 | ((unsigned int)l1 << 16);
        }
        PH.x = ph[0]; PH.y = ph[1]; PH.z = ph[2]; PH.w = ph[3];
        PL.x = pl[0]; PL.y = pl[1]; PL.z = pl[2]; PL.w = pl[3];
        int off = r * 256 + ((2 * k) ^ ((r & 7) << 4));   // 16B-slot XOR swizzle
        *(uint4*)((char*)xsh + off) = PH;
        *(uint4*)((char*)xsl + off) = PL;
    }
    __syncthreads();

    f4x acc[4][2];
#pragma unroll
    for (int m = 0; m < 4; ++m)
#pragma unroll
        for (int t = 0; t < 2; ++t) acc[m][t] = (f4x){0.f, 0.f, 0.f, 0.f};

#pragma unroll
    for (int s = 0; s < 4; ++s) {
#pragma unroll
        for (int m = 0; m < 4; ++m) {
            int row = 16 * m + li;
            int kb = (32 * s + 8 * g) * 2;
            int off = row * 256 + (kb ^ ((row & 7) << 4));
            h8 ah = *(const h8*)((const char*)xsh + off);
            h8 al = *(const h8*)((const char*)xsl + off);
#pragma unroll
            for (int t = 0; t < 2; ++t) {
                acc[m][t] = __builtin_amdgcn_mfma_f32_16x16x32_f16(ah, Bh[t][s], acc[m][t], 0, 0, 0);
                acc[m][t] = __builtin_amdgcn_mfma_f32_16x16x32_f16(al, Bh[t][s], acc[m][t], 0, 0, 0);
                acc[m][t] = __builtin_amdgcn_mfma_f32_16x16x32_f16(ah, Bl[t][s], acc[m][t], 0, 0, 0);
            }
        }
    }

    // Epilogue 1: attn dots from fp32 acc. C/D: col = li, row = 4*g + reg.
    float at_s0 = attf[c0 + li],       at_s1 = attf[c0 + 16 + li];
    float at_d0 = attf[128 + c0 + li], at_d1 = attf[128 + c0 + 16 + li];
#pragma unroll
    for (int m = 0; m < 4; ++m) {
        float s1v[4], s2v[4];
#pragma unroll
        for (int j = 0; j < 4; ++j) {
            s1v[j] = acc[m][0][j] * at_s0 + acc[m][1][j] * at_s1;
            s2v[j] = acc[m][0][j] * at_d0 + acc[m][1][j] * at_d1;
        }
#pragma unroll
        for (int j = 0; j < 4; ++j) {
#pragma unroll
            for (int msk = 1; msk < 16; msk <<= 1) {
                s1v[j] += __shfl_xor(s1v[j], msk);
                s2v[j] += __shfl_xor(s2v[j], msk);
            }
        }
        if (li == 0) {
#pragma unroll
            for (int j = 0; j < 4; ++j) {
                int gr = r0 + 16 * m + 4 * g + j;
                if (gr < N) {
                    asf[(size_t)gr * 4 + w] = s1v[j];
                    adf[(size_t)gr * 4 + w] = s2v[j];
                }
            }
        }
    }

    // Epilogue 2: h -> bf16 via LDS (reuse hi-plane) for coalesced store.
    __syncthreads();
#pragma unroll
    for (int m = 0; m < 4; ++m)
#pragma unroll
        for (int t = 0; t < 2; ++t)
#pragma unroll
            for (int j = 0; j < 4; ++j)
                xsh[(16 * m + 4 * g + j) * 128 + c0 + 16 * t + li] = f2b(acc[m][t][j]);
    __syncthreads();
#pragma unroll
    for (int it = 0; it < 4; ++it) {
        int u = it * 2048 + tid * 8;
        int r = u >> 7, k = u & 127;
        int gr = r0 + r;
        if (gr < N)
            *(uint4*)(hbf + (size_t)gr * 128 + k) = *(const uint4*)(xsh + u);
    }
}

// --- 1b. demux: bucket entries -> exact per-node cnt/esrc -------------------
__global__ __launch_bounds__(256) void k_demux(
    const unsigned* __restrict__ bdat, const int* __restrict__ bcnt,
    int* __restrict__ cnt, int* __restrict__ esrc, int N) {
    __shared__ int lcnt[64];
    __shared__ int lslot[64][64];
    int b = blockIdx.x;
    int tid = threadIdx.x;
    if (tid < 64) lcnt[tid] = 0;
    __syncthreads();
    int m = bcnt[b];
    int ovf = (m > BCAP);
    if (m > BCAP) m = BCAP;
    for (int i = tid; i < m; i += 256) {
        unsigned e = bdat[(size_t)b * BCAP + i];
        int dl = (int)(e >> 26);
        int s  = (int)(e & 0x03FFFFFFu);
        int p = atomicAdd(&lcnt[dl], 1);
        if (p < SLOT) lslot[dl][p] = s;
    }
    __syncthreads();
    int n0 = b << 6;
    for (int i = tid; i < 1024; i += 256) {      // 64 rows x 16 int4 each
        int row = i >> 4;
        if (n0 + row < N)
            *(int4*)(esrc + (size_t)(n0 + row) * SLOT + (i & 15) * 4) =
                ((const int4*)lslot)[i];
    }
    if (tid < 64 && n0 + tid < N)
        cnt[(size_t)(n0 + tid) * CNTS] = ovf ? (SLOT + 1) : lcnt[tid];
}

// --- 2. aggregate: one wave per node; self-loop = lane 0 (unchanged) --------
__global__ __launch_bounds__(256) void k_aggregate(
    const unsigned short* __restrict__ hbf,
    const float* __restrict__ asf, const float* __restrict__ adf,
    const int* __restrict__ cnt, const int* __restrict__ esrc,
    const int* __restrict__ idx32, const long long* __restrict__ idx64,
    const float* __restrict__ biasf, const int* __restrict__ flags,
    void* __restrict__ outv, int N, int E) {
    __shared__ float p_sh_all[4][SLOT * 4];
    __shared__ int   s_sh_all[4][SLOT];
    int wid = threadIdx.x >> 6;
    int lane = threadIdx.x & 63;
    int n = blockIdx.x * 4 + wid;
    if (n >= N) n = N - 1;                     // tail waves redo a node (benign)
    float* p_sh = p_sh_all[wid];
    int*   s_sh = s_sh_all[wid];
    int head = lane >> 4;

    int deg = cnt[(size_t)n * CNTS];           // edges, excl. self-loop
    float4 adv = *(const float4*)(adf + (size_t)n * 4);
    bool fb = (deg > SLOT - 1);                // total deg+1 must fit in 64

    float p0 = 0.f, p1 = 0.f, p2 = 0.f, p3 = 0.f;
    if (!fb && lane <= deg) {                  // phase 1: one item per lane
        int s = (lane == 0) ? n : esrc[(size_t)n * SLOT + lane - 1];
        float4 av = *(const float4*)(asf + (size_t)s * 4);
        float e0 = av.x + adv.x; e0 = fmaxf(e0, 0.2f * e0); p0 = __expf(e0);
        float e1 = av.y + adv.y; e1 = fmaxf(e1, 0.2f * e1); p1 = __expf(e1);
        float e2 = av.z + adv.z; e2 = fmaxf(e2, 0.2f * e2); p2 = __expf(e2);
        float e3 = av.w + adv.w; e3 = fmaxf(e3, 0.2f * e3); p3 = __expf(e3);
        s_sh[lane] = s;
        p_sh[lane * 4 + 0] = p0; p_sh[lane * 4 + 1] = p1;
        p_sh[lane * 4 + 2] = p2; p_sh[lane * 4 + 3] = p3;
    }
    __syncthreads();

    float b0 = biasf[2 * lane], b1 = biasf[2 * lane + 1];
    float a0 = 0.f, a1 = 0.f, invh;

    if (!fb) {
        float ps0 = p0, ps1 = p1, ps2 = p2, ps3 = p3;
#pragma unroll
        for (int m = 1; m < 64; m <<= 1) {     // 64-lane butterfly
            ps0 += __shfl_xor(ps0, m);
            ps1 += __shfl_xor(ps1, m);
            ps2 += __shfl_xor(ps2, m);
            ps3 += __shfl_xor(ps3, m);
        }
        float den = head == 0 ? ps0 : head == 1 ? ps1 : head == 2 ? ps2 : ps3;
        invh = 1.0f / (den + 1e-16f);

        int tot = deg + 1;
        int i = 0;
        for (; i + 3 < tot; i += 4) {          // 4 row-gathers in flight
            int s0 = s_sh[i], s1 = s_sh[i + 1], s2 = s_sh[i + 2], s3 = s_sh[i + 3];
            float q0 = p_sh[i * 4 + head],       q1 = p_sh[(i + 1) * 4 + head];
            float q2 = p_sh[(i + 2) * 4 + head], q3 = p_sh[(i + 3) * 4 + head];
            unsigned int v0 = *(const unsigned int*)(hbf + (size_t)s0 * 128 + 2 * lane);
            unsigned int v1 = *(const unsigned int*)(hbf + (size_t)s1 * 128 + 2 * lane);
            unsigned int v2 = *(const unsigned int*)(hbf + (size_t)s2 * 128 + 2 * lane);
            unsigned int v3 = *(const unsigned int*)(hbf + (size_t)s3 * 128 + 2 * lane);
            a0 += q0 * b2f((unsigned short)v0) + q1 * b2f((unsigned short)v1)
                + q2 * b2f((unsigned short)v2) + q3 * b2f((unsigned short)v3);
            a1 += q0 * b2f((unsigned short)(v0 >> 16)) + q1 * b2f((unsigned short)(v1 >> 16))
                + q2 * b2f((unsigned short)(v2 >> 16)) + q3 * b2f((unsigned short)(v3 >> 16));
        }
        for (; i < tot; ++i) {
            int s0 = s_sh[i];
            float q0 = p_sh[i * 4 + head];
            unsigned int v0 = *(const unsigned int*)(hbf + (size_t)s0 * 128 + 2 * lane);
            a0 += q0 * b2f((unsigned short)v0);
            a1 += q0 * b2f((unsigned short)(v0 >> 16));
        }
    } else {
        // parachute: degree >= SLOT or bucket overflow. Full edge rescan.
        int is64 = flags[0];
        float adh = head == 0 ? adv.x : head == 1 ? adv.y : head == 2 ? adv.z : adv.w;
        float den = 0.f;
        {   // self-loop
            float ev = asf[(size_t)n * 4 + head] + adh; ev = fmaxf(ev, 0.2f * ev);
            float p = __expf(ev);
            unsigned int v = *(const unsigned int*)(hbf + (size_t)n * 128 + 2 * lane);
            den += p;
            a0 += p * b2f((unsigned short)v);
            a1 += p * b2f((unsigned short)(v >> 16));
        }
        for (int e = 0; e < E; ++e) {
            int d = edge_at(idx32, idx64, is64, (long long)E + e);
            if (d == n) {
                int s = edge_at(idx32, idx64, is64, e);
                float ev = asf[(size_t)s * 4 + head] + adh; ev = fmaxf(ev, 0.2f * ev);
                float p = __expf(ev);
                unsigned int v = *(const unsigned int*)(hbf + (size_t)s * 128 + 2 * lane);
                den += p;
                a0 += p * b2f((unsigned short)v);
                a1 += p * b2f((unsigned short)(v >> 16));
            }
        }
        invh = 1.0f / (den + 1e-16f);
    }

    a0 = a0 * invh + b0;
    a1 = a1 * invh + b1;
    if (flags[1]) {
        unsigned int pk = (unsigned int)f2b(a0) | ((unsigned int)f2b(a1) << 16);
        ((unsigned int*)outv)[(size_t)n * 64 + lane] = pk;
    } else {
        float2 f2; f2.x = a0; f2.y = a1;
        *(float2*)((float*)outv + (size_t)n * 128 + 2 * lane) = f2;
    }
}

// ---------------------------------------------------------------------------
extern "C" void kernel_launch(void* const* d_in, const int* in_sizes, int n_in,
                              void* d_out, int out_size, void* d_ws, size_t ws_size,
                              hipStream_t stream) {
    const void*      xv    = d_in[0];
    const int*       idx32 = (const int*)d_in[1];
    const long long* idx64 = (const long long*)d_in[1];

    int N = in_sizes[0] / 128;
    int E = in_sizes[1] / 2;

    char* ws = (char*)d_ws;
    size_t o = 0;
    auto alloc = [&](size_t bytes) {
        size_t r = o; o += (bytes + 255) & ~(size_t)255; return r;
    };
    unsigned short* hbf = (unsigned short*)(ws + alloc((size_t)N * 128 * 2));
    _Float16* Wth = (_Float16*)(ws + alloc(16384 * 2));
    _Float16* Wtl = (_Float16*)(ws + alloc(16384 * 2));
    float* attf  = (float*)(ws + alloc(256 * 4));
    float* biasf = (float*)(ws + alloc(128 * 4));
    float* asf   = (float*)(ws + alloc((size_t)N * 4 * 4));
    float* adf   = (float*)(ws + alloc((size_t)N * 4 * 4));
    int* cnt     = (int*)(ws + alloc((size_t)N * CNTS * 4));
    int* flags   = (int*)(ws + alloc(256));
    int* esrc    = (int*)(ws + alloc((size_t)N * SLOT * 4));
    int NBK = (N + 63) >> 6;
    int* bcnt      = (int*)(ws + alloc((size_t)NBK * 4));
    unsigned* bdat = (unsigned*)(ws + alloc((size_t)NBK * BCAP * 4));

    int Gg = (N + 63) / 64;                  // gemm tiles (64 rows each)
    int SB = (E + KCH - 1) / KCH;            // scatter chunks
    int NB = SB + Gg;

    k_detect<<<1, 256, 0, stream>>>(idx32, (const unsigned int*)xv, flags);
    k_prep<<<16, 256, 0, stream>>>(d_in[2], d_in[3], d_in[4], d_in[5], flags, Wth, Wtl, attf, biasf);
    if (NBK <= MAXB) {
        hipMemsetAsync(bcnt, 0, (size_t)NBK * 4, stream);
        k_gemm_scatter<<<NB, 256, 0, stream>>>(xv, Wth, Wtl, attf, flags, hbf, asf, adf, N,
                                               idx32, idx64, bcnt, bdat, cnt, esrc, E, Gg, SB);
        k_demux<<<NBK, 256, 0, stream>>>(bdat, bcnt, cnt, esrc, N);
    } else {
        hipMemsetAsync(cnt, 0, (size_t)N * CNTS * 4, stream);
        k_gemm_scatter<<<NB, 256, 0, stream>>>(xv, Wth, Wtl, attf, flags, hbf, asf, adf, N,
                                               idx32, idx64, bcnt, bdat, cnt, esrc, E, Gg, SB);
    }
    k_aggregate<<<(N + 3) / 4, 256, 0, stream>>>(hbf, asf, adf, cnt, esrc, idx32, idx64,
                                                 biasf, flags, d_out, N, E);
}

// Round 4
// 267.972 us; speedup vs baseline: 1.1422x; 1.0139x over previous
//
#include <hip/hip_runtime.h>
#include <stdint.h>

// ---------------------------------------------------------------------------
// GAT layer, dtype-adaptive (probed: fp32 inputs, int32 edge_index, bf16 out).
//   fused:  h = x@W via split-f16 MFMA (fp32-grade), attn dots in epilogue
//           [blocks SB..SB+Gg)]
//           bucketed scatter: 64-node buckets, PER-WAVE LDS histograms +
//           one device atomic per (block,bucket) run-claim, per-wave cursor
//           sub-runs (intra-wave RMW only), KCH=8192 for 2x CU spread
//           [blocks 0..SB)]
//   bagg:   fused demux+aggregate, one block per bucket: entries -> LDS CSR,
//           then 4 waves x 16 nodes each aggregate straight from LDS.
//           8-deep h-row gather pipeline. No esrc/cnt global round-trip.
//   legacy (N > 131072): per-edge scatter into cnt/esrc + old k_aggregate.
// ---------------------------------------------------------------------------

#define SLOT 64
#define CNTS 16    // counter stride in ints (legacy path)
#define BCAP 1536  // bucket capacity (entries); avg fill 1024, ~16 sigma slack
#define MAXB 2048  // max buckets (N <= 131072); 4 per-wave hists = 32KB LDS
#define KCH  8192  // edges per scatter chunk

typedef __attribute__((ext_vector_type(8))) _Float16 h8;
typedef __attribute__((ext_vector_type(4))) float    f4x;

__device__ __forceinline__ float b2f(unsigned short u) {
    union { unsigned int i; float f; } v; v.i = ((unsigned int)u) << 16; return v.f;
}
__device__ __forceinline__ unsigned short f2b(float f) {
    union { float f; unsigned int i; } v; v.f = f;
    unsigned int i = v.i;
    unsigned int r = (i + 0x7FFFu + ((i >> 16) & 1u)) >> 16;  // RNE
    return (unsigned short)r;
}
__device__ __forceinline__ unsigned short f2h(float f) {
    union { _Float16 h; unsigned short u; } v; v.h = (_Float16)f; return v.u;
}
__device__ __forceinline__ float h2f(unsigned short u) {
    union { _Float16 h; unsigned short u; } v; v.u = u; return (float)v.h;
}

// --- 0. dtype probes --------------------------------------------------------
__global__ void k_detect(const int* __restrict__ eidx, const unsigned int* __restrict__ xw,
                         int* flags) {
    __shared__ int nz, bf;
    if (threadIdx.x == 0) { nz = 0; bf = 0; }
    __syncthreads();
    int bad = 0;
    for (int i = threadIdx.x; i < 1024; i += 256)
        if (eidx[2 * i + 1] != 0) bad = 1;
    if (bad) atomicOr(&nz, 1);
    int hits = 0;
    for (int i = threadIdx.x; i < 4096; i += 256) {
        unsigned int e = (xw[i] >> 7) & 0xFFu;
        if (e >= 0x60u && e < 0xA0u) ++hits;
    }
    atomicAdd(&bf, hits);
    __syncthreads();
    if (threadIdx.x == 0) {
        flags[0] = (nz == 0) ? 1 : 0;   // 1 => int64 edge_index
        flags[1] = (bf > 3072) ? 1 : 0; // 1 => bf16 float tensors
    }
}

__device__ __forceinline__ int edge_at(const int* idx32, const long long* idx64,
                                       int is64, long long pos) {
    return is64 ? (int)idx64[pos] : idx32[pos];
}

// --- 0b. W^T hi/lo f16 + att/bias fp32 -> ws --------------------------------
__global__ void k_prep(const void* __restrict__ Wv, const void* __restrict__ asv,
                       const void* __restrict__ adv, const void* __restrict__ bv,
                       const int* __restrict__ flags,
                       _Float16* __restrict__ Wth, _Float16* __restrict__ Wtl,
                       float* __restrict__ attf /*256*/, float* __restrict__ biasf /*128*/) {
    int isbf = flags[1];
    int tid = blockIdx.x * 256 + threadIdx.x;
    for (int i = tid; i < 16384; i += gridDim.x * 256) {
        int col = i >> 7, k = i & 127;            // Wt[col][k] = W[k][col]
        float w = isbf ? b2f(((const unsigned short*)Wv)[k * 128 + col])
                       : ((const float*)Wv)[k * 128 + col];
        unsigned short hi = f2h(w);
        unsigned short lo = f2h(w - h2f(hi));
        ((unsigned short*)Wth)[i] = hi;
        ((unsigned short*)Wtl)[i] = lo;
    }
    if (blockIdx.x == 0) {
        for (int i = threadIdx.x; i < 128; i += 256) {
            attf[i]       = isbf ? b2f(((const unsigned short*)asv)[i]) : ((const float*)asv)[i];
            attf[128 + i] = isbf ? b2f(((const unsigned short*)adv)[i]) : ((const float*)adv)[i];
            biasf[i]      = isbf ? b2f(((const unsigned short*)bv)[i]) : ((const float*)bv)[i];
        }
    }
}

// --- 1. fused MFMA GEMM (blocks >= SB) + bucketed scatter (blocks < SB) -----
__global__ __launch_bounds__(256) void k_gemm_scatter(
    const void* __restrict__ xv,
    const _Float16* __restrict__ Wth, const _Float16* __restrict__ Wtl,
    const float* __restrict__ attf, const int* __restrict__ flags,
    unsigned short* __restrict__ hbf, float* __restrict__ asf,
    float* __restrict__ adf, int N,
    const int* __restrict__ idx32, const long long* __restrict__ idx64,
    int* __restrict__ bcnt, unsigned* __restrict__ bdat,
    int* __restrict__ cnt, int* __restrict__ esrc,
    int E, int Gg, int SB) {
    __shared__ unsigned short xsh[64 * 128];   // x hi-plane / scatter hists 0,1
    __shared__ unsigned short xsl[64 * 128];   // x lo-plane / scatter hists 2,3
    int tid = threadIdx.x;
    int bid = blockIdx.x;

    if (bid < SB) {                            // ---- bucketed scatter ----
        int is64 = flags[0];
        int NBK = (N + 63) >> 6;
        long long e0 = (long long)bid * KCH;
        long long e1 = e0 + KCH; if (e1 > E) e1 = E;
        if (e0 >= E) return;

        if (NBK <= MAXB) {
            int wid = tid >> 6;
            int* h0 = (int*)xsh; int* h1 = h0 + MAXB;
            int* h2 = (int*)xsl; int* h3 = h2 + MAXB;
            int* hw = (wid == 0) ? h0 : (wid == 1) ? h1 : (wid == 2) ? h2 : h3;
            for (int i = tid; i < NBK; i += 256) { h0[i] = 0; h1[i] = 0; h2[i] = 0; h3[i] = 0; }
            __syncthreads();
            // pass 1: per-wave chunk histograms (intra-wave RMW only)
            for (long long e = e0 + tid; e < e1; e += 256) {
                int d = is64 ? (int)idx64[(long long)E + e] : idx32[E + e];
                atomicAdd(&hw[d >> 6], 1);
            }
            __syncthreads();
            // claim: ONE device atomic per non-empty bucket; per-wave sub-runs
            for (int b = tid; b < NBK; b += 256) {
                int c0 = h0[b], c1 = h1[b], c2 = h2[b], c3 = h3[b];
                int t = c0 + c1 + c2 + c3;
                int base = (t > 0) ? atomicAdd(&bcnt[b], t) : 0;
                h0[b] = base;
                h1[b] = base + c0;
                h2[b] = base + c0 + c1;
                h3[b] = base + c0 + c1 + c2;
            }
            __syncthreads();
            // pass 2: place entries at per-wave LDS cursors
            for (long long e = e0 + tid; e < e1; e += 256) {
                int d, s;
                if (is64) {
                    d = (int)idx64[(long long)E + e]; s = (int)idx64[e];
                } else {
                    d = idx32[E + e]; s = idx32[e];
                }
                int b = d >> 6;
                int p = atomicAdd(&hw[b], 1);
                if (p < BCAP)
                    bdat[(size_t)b * BCAP + p] = (unsigned)s | ((unsigned)(d & 63) << 26);
            }
        } else {
            // legacy per-edge path (host memsets cnt, uses old k_aggregate)
            for (long long e = e0 + tid; e < e1; e += 256) {
                int d = edge_at(idx32, idx64, is64, (long long)E + e);
                int s = edge_at(idx32, idx64, is64, e);
                int p = atomicAdd(&cnt[(size_t)d * CNTS], 1);
                if (p < SLOT) esrc[(size_t)d * SLOT + p] = s;
            }
        }
        return;
    }

    // ---- MFMA GEMM (unchanged) ----
    int rb = bid - SB;
    if (rb >= Gg) return;
    int r0 = rb * 64;
    int isbf = flags[1];
    int w = tid >> 6;            // wave id = head id (owns cols [32w, 32w+32))
    int lane = tid & 63;
    int li = lane & 15;          // fragment row/col index
    int g  = lane >> 4;          // k-group
    int c0 = w * 32;

    h8 Bh[2][4], Bl[2][4];
#pragma unroll
    for (int t = 0; t < 2; ++t)
#pragma unroll
        for (int s = 0; s < 4; ++s) {
            size_t o = (size_t)(c0 + 16 * t + li) * 128 + 32 * s + 8 * g;
            Bh[t][s] = *(const h8*)(Wth + o);
            Bl[t][s] = *(const h8*)(Wtl + o);
        }

#pragma unroll
    for (int it = 0; it < 4; ++it) {
        int idx = it * 2048 + tid * 8;         // 8 elements per thread per iter
        int r = idx >> 7, k = idx & 127;
        int gr = r0 + r; if (gr >= N) gr = N - 1;
        float v[8];
        if (isbf) {
            uint4 raw = *(const uint4*)((const unsigned short*)xv + (size_t)gr * 128 + k);
            v[0] = b2f((unsigned short)(raw.x & 0xFFFFu)); v[1] = b2f((unsigned short)(raw.x >> 16));
            v[2] = b2f((unsigned short)(raw.y & 0xFFFFu)); v[3] = b2f((unsigned short)(raw.y >> 16));
            v[4] = b2f((unsigned short)(raw.z & 0xFFFFu)); v[5] = b2f((unsigned short)(raw.z >> 16));
            v[6] = b2f((unsigned short)(raw.w & 0xFFFFu)); v[7] = b2f((unsigned short)(raw.w >> 16));
        } else {
            const float* xf = (const float*)xv;
            float4 a = *(const float4*)(xf + (size_t)gr * 128 + k);
            float4 b = *(const float4*)(xf + (size_t)gr * 128 + k + 4);
            v[0] = a.x; v[1] = a.y; v[2] = a.z; v[3] = a.w;
            v[4] = b.x; v[5] = b.y; v[6] = b.z; v[7] = b.w;
        }
        uint4 PH, PL;
        unsigned int ph[4], pl[4];
#pragma unroll
        for (int jj = 0; jj < 4; ++jj) {
            unsigned short h0 = f2h(v[2 * jj]), h1 = f2h(v[2 * jj + 1]);
            unsigned short l0 = f2h(v[2 * jj] - h2f(h0));
            unsigned short l1 = f2h(v[2 * jj + 1] - h2f(h1));
            ph[jj] = (unsigned int)h0 | ((unsigned int)h1 << 16);
            pl[jj] = (unsigned int)l0 | ((unsigned int)l1 << 16);
        }
        PH.x = ph[0]; PH.y = ph[1]; PH.z = ph[2]; PH.w = ph[3];
        PL.x = pl[0]; PL.y = pl[1]; PL.z = pl[2]; PL.w = pl[3];
        int off = r * 256 + ((2 * k) ^ ((r & 7) << 4));   // 16B-slot XOR swizzle
        *(uint4*)((char*)xsh + off) = PH;
        *(uint4*)((char*)xsl + off) = PL;
    }
    __syncthreads();

    f4x acc[4][2];
#pragma unroll
    for (int m = 0; m < 4; ++m)
#pragma unroll
        for (int t = 0; t < 2; ++t) acc[m][t] = (f4x){0.f, 0.f, 0.f, 0.f};

#pragma unroll
    for (int s = 0; s < 4; ++s) {
#pragma unroll
        for (int m = 0; m < 4; ++m) {
            int row = 16 * m + li;
            int kb = (32 * s + 8 * g) * 2;
            int off = row * 256 + (kb ^ ((row & 7) << 4));
            h8 ah = *(const h8*)((const char*)xsh + off);
            h8 al = *(const h8*)((const char*)xsl + off);
#pragma unroll
            for (int t = 0; t < 2; ++t) {
                acc[m][t] = __builtin_amdgcn_mfma_f32_16x16x32_f16(ah, Bh[t][s], acc[m][t], 0, 0, 0);
                acc[m][t] = __builtin_amdgcn_mfma_f32_16x16x32_f16(al, Bh[t][s], acc[m][t], 0, 0, 0);
                acc[m][t] = __builtin_amdgcn_mfma_f32_16x16x32_f16(ah, Bl[t][s], acc[m][t], 0, 0, 0);
            }
        }
    }

    // Epilogue 1: attn dots from fp32 acc. C/D: col = li, row = 4*g + reg.
    float at_s0 = attf[c0 + li],       at_s1 = attf[c0 + 16 + li];
    float at_d0 = attf[128 + c0 + li], at_d1 = attf[128 + c0 + 16 + li];
#pragma unroll
    for (int m = 0; m < 4; ++m) {
        float s1v[4], s2v[4];
#pragma unroll
        for (int j = 0; j < 4; ++j) {
            s1v[j] = acc[m][0][j] * at_s0 + acc[m][1][j] * at_s1;
            s2v[j] = acc[m][0][j] * at_d0 + acc[m][1][j] * at_d1;
        }
#pragma unroll
        for (int j = 0; j < 4; ++j) {
#pragma unroll
            for (int msk = 1; msk < 16; msk <<= 1) {
                s1v[j] += __shfl_xor(s1v[j], msk);
                s2v[j] += __shfl_xor(s2v[j], msk);
            }
        }
        if (li == 0) {
#pragma unroll
            for (int j = 0; j < 4; ++j) {
                int gr = r0 + 16 * m + 4 * g + j;
                if (gr < N) {
                    asf[(size_t)gr * 4 + w] = s1v[j];
                    adf[(size_t)gr * 4 + w] = s2v[j];
                }
            }
        }
    }

    // Epilogue 2: h -> bf16 via LDS (reuse hi-plane) for coalesced store.
    __syncthreads();
#pragma unroll
    for (int m = 0; m < 4; ++m)
#pragma unroll
        for (int t = 0; t < 2; ++t)
#pragma unroll
            for (int j = 0; j < 4; ++j)
                xsh[(16 * m + 4 * g + j) * 128 + c0 + 16 * t + li] = f2b(acc[m][t][j]);
    __syncthreads();
#pragma unroll
    for (int it = 0; it < 4; ++it) {
        int u = it * 2048 + tid * 8;
        int r = u >> 7, k = u & 127;
        int gr = r0 + r;
        if (gr < N)
            *(uint4*)(hbf + (size_t)gr * 128 + k) = *(const uint4*)(xsh + u);
    }
}

// --- 2. fused demux + aggregate: one block per 64-node bucket ---------------
__global__ __launch_bounds__(256) void k_bagg(
    const unsigned* __restrict__ bdat, const int* __restrict__ bcnt,
    const unsigned short* __restrict__ hbf,
    const float* __restrict__ asf, const float* __restrict__ adf,
    const int* __restrict__ idx32, const long long* __restrict__ idx64,
    const float* __restrict__ biasf, const int* __restrict__ flags,
    void* __restrict__ outv, int N, int E) {
    __shared__ int   lcnt[64];
    __shared__ int   lslot[64][SLOT];          // 16KB
    __shared__ float p_all[4][SLOT * 4];       // 4KB, per-wave transient
    int b = blockIdx.x, tid = threadIdx.x;
    int wid = tid >> 6, lane = tid & 63, head = lane >> 4;

    if (tid < 64) lcnt[tid] = 0;
    __syncthreads();
    int mm = bcnt[b];
    int ovf = (mm > BCAP);
    if (mm > BCAP) mm = BCAP;
    for (int i = tid; i < mm; i += 256) {      // demux bucket -> LDS CSR
        unsigned e = bdat[(size_t)b * BCAP + i];
        int dl = (int)(e >> 26);
        int p = atomicAdd(&lcnt[dl], 1);
        if (p < SLOT) lslot[dl][p] = (int)(e & 0x03FFFFFFu);
    }
    __syncthreads();

    float b0 = biasf[2 * lane], b1 = biasf[2 * lane + 1];
    float* psh = p_all[wid];
    int isbf = flags[1];
    int is64 = flags[0];

    for (int u = 0; u < 16; ++u) {             // 16 nodes per wave, no block sync
        int dl = wid * 16 + u;
        int n = (b << 6) + dl;
        if (n >= N) break;                     // wave-uniform
        int deg = lcnt[dl];
        bool fb = ovf || (deg > SLOT - 1);
        float4 adv = *(const float4*)(adf + (size_t)n * 4);
        float a0 = 0.f, a1 = 0.f, invh;

        if (!fb) {
            float p0 = 0.f, p1 = 0.f, p2 = 0.f, p3 = 0.f;
            if (lane <= deg) {                 // item per lane: 0=self, k=edge k-1
                int s = (lane == 0) ? n : lslot[dl][lane - 1];
                float4 av = *(const float4*)(asf + (size_t)s * 4);
                float e0 = av.x + adv.x; e0 = fmaxf(e0, 0.2f * e0); p0 = __expf(e0);
                float e1 = av.y + adv.y; e1 = fmaxf(e1, 0.2f * e1); p1 = __expf(e1);
                float e2 = av.z + adv.z; e2 = fmaxf(e2, 0.2f * e2); p2 = __expf(e2);
                float e3 = av.w + adv.w; e3 = fmaxf(e3, 0.2f * e3); p3 = __expf(e3);
                psh[lane * 4 + 0] = p0; psh[lane * 4 + 1] = p1;
                psh[lane * 4 + 2] = p2; psh[lane * 4 + 3] = p3;
            }
            __builtin_amdgcn_wave_barrier();
            asm volatile("s_waitcnt lgkmcnt(0)" ::: "memory");
            __builtin_amdgcn_wave_barrier();

            float ps0 = p0, ps1 = p1, ps2 = p2, ps3 = p3;
#pragma unroll
            for (int m = 1; m < 64; m <<= 1) { // 64-lane butterfly denom
                ps0 += __shfl_xor(ps0, m);
                ps1 += __shfl_xor(ps1, m);
                ps2 += __shfl_xor(ps2, m);
                ps3 += __shfl_xor(ps3, m);
            }
            float den = head == 0 ? ps0 : head == 1 ? ps1 : head == 2 ? ps2 : ps3;
            invh = 1.0f / (den + 1e-16f);

            {   // self-loop gather (item 0)
                unsigned v = *(const unsigned int*)(hbf + (size_t)n * 128 + 2 * lane);
                float q = psh[head];
                a0 += q * b2f((unsigned short)v);
                a1 += q * b2f((unsigned short)(v >> 16));
            }
            int j = 0;
            for (; j + 7 < deg; j += 8) {      // 8 row-gathers in flight
                unsigned vv[8]; float qq[8];
#pragma unroll
                for (int k2 = 0; k2 < 8; ++k2) {
                    int s = lslot[dl][j + k2];
                    qq[k2] = psh[(j + 1 + k2) * 4 + head];
                    vv[k2] = *(const unsigned int*)(hbf + (size_t)s * 128 + 2 * lane);
                }
#pragma unroll
                for (int k2 = 0; k2 < 8; ++k2) {
                    a0 += qq[k2] * b2f((unsigned short)vv[k2]);
                    a1 += qq[k2] * b2f((unsigned short)(vv[k2] >> 16));
                }
            }
            for (; j + 3 < deg; j += 4) {
                unsigned vv[4]; float qq[4];
#pragma unroll
                for (int k2 = 0; k2 < 4; ++k2) {
                    int s = lslot[dl][j + k2];
                    qq[k2] = psh[(j + 1 + k2) * 4 + head];
                    vv[k2] = *(const unsigned int*)(hbf + (size_t)s * 128 + 2 * lane);
                }
#pragma unroll
                for (int k2 = 0; k2 < 4; ++k2) {
                    a0 += qq[k2] * b2f((unsigned short)vv[k2]);
                    a1 += qq[k2] * b2f((unsigned short)(vv[k2] >> 16));
                }
            }
            for (; j < deg; ++j) {
                int s = lslot[dl][j];
                float q = psh[(j + 1) * 4 + head];
                unsigned v = *(const unsigned int*)(hbf + (size_t)s * 128 + 2 * lane);
                a0 += q * b2f((unsigned short)v);
                a1 += q * b2f((unsigned short)(v >> 16));
            }
        } else {
            // parachute: deg >= SLOT or bucket overflow. Exact full rescan.
            float adh = head == 0 ? adv.x : head == 1 ? adv.y : head == 2 ? adv.z : adv.w;
            float den = 0.f;
            {   // self-loop
                float ev = asf[(size_t)n * 4 + head] + adh; ev = fmaxf(ev, 0.2f * ev);
                float p = __expf(ev);
                unsigned int v = *(const unsigned int*)(hbf + (size_t)n * 128 + 2 * lane);
                den += p;
                a0 += p * b2f((unsigned short)v);
                a1 += p * b2f((unsigned short)(v >> 16));
            }
            for (int e = 0; e < E; ++e) {
                int d = edge_at(idx32, idx64, is64, (long long)E + e);
                if (d == n) {
                    int s = edge_at(idx32, idx64, is64, e);
                    float ev = asf[(size_t)s * 4 + head] + adh; ev = fmaxf(ev, 0.2f * ev);
                    float p = __expf(ev);
                    unsigned int v = *(const unsigned int*)(hbf + (size_t)s * 128 + 2 * lane);
                    den += p;
                    a0 += p * b2f((unsigned short)v);
                    a1 += p * b2f((unsigned short)(v >> 16));
                }
            }
            invh = 1.0f / (den + 1e-16f);
        }

        a0 = a0 * invh + b0;
        a1 = a1 * invh + b1;
        if (isbf) {
            unsigned int pk = (unsigned int)f2b(a0) | ((unsigned int)f2b(a1) << 16);
            ((unsigned int*)outv)[(size_t)n * 64 + lane] = pk;
        } else {
            float2 f2; f2.x = a0; f2.y = a1;
            *(float2*)((float*)outv + (size_t)n * 128 + 2 * lane) = f2;
        }
        __builtin_amdgcn_wave_barrier();
    }
}

// --- 2L. legacy aggregate (NBK > MAXB only): one wave per node --------------
__global__ __launch_bounds__(256) void k_aggregate(
    const unsigned short* __restrict__ hbf,
    const float* __restrict__ asf, const float* __restrict__ adf,
    const int* __restrict__ cnt, const int* __restrict__ esrc,
    const int* __restrict__ idx32, const long long* __restrict__ idx64,
    const float* __restrict__ biasf, const int* __restrict__ flags,
    void* __restrict__ outv, int N, int E) {
    __shared__ float p_sh_all[4][SLOT * 4];
    __shared__ int   s_sh_all[4][SLOT];
    int wid = threadIdx.x >> 6;
    int lane = threadIdx.x & 63;
    int n = blockIdx.x * 4 + wid;
    if (n >= N) n = N - 1;                     // tail waves redo a node (benign)
    float* p_sh = p_sh_all[wid];
    int*   s_sh = s_sh_all[wid];
    int head = lane >> 4;

    int deg = cnt[(size_t)n * CNTS];           // edges, excl. self-loop
    float4 adv = *(const float4*)(adf + (size_t)n * 4);
    bool fb = (deg > SLOT - 1);                // total deg+1 must fit in 64

    float p0 = 0.f, p1 = 0.f, p2 = 0.f, p3 = 0.f;
    if (!fb && lane <= deg) {                  // phase 1: one item per lane
        int s = (lane == 0) ? n : esrc[(size_t)n * SLOT + lane - 1];
        float4 av = *(const float4*)(asf + (size_t)s * 4);
        float e0 = av.x + adv.x; e0 = fmaxf(e0, 0.2f * e0); p0 = __expf(e0);
        float e1 = av.y + adv.y; e1 = fmaxf(e1, 0.2f * e1); p1 = __expf(e1);
        float e2 = av.z + adv.z; e2 = fmaxf(e2, 0.2f * e2); p2 = __expf(e2);
        float e3 = av.w + adv.w; e3 = fmaxf(e3, 0.2f * e3); p3 = __expf(e3);
        s_sh[lane] = s;
        p_sh[lane * 4 + 0] = p0; p_sh[lane * 4 + 1] = p1;
        p_sh[lane * 4 + 2] = p2; p_sh[lane * 4 + 3] = p3;
    }
    __syncthreads();

    float b0 = biasf[2 * lane], b1 = biasf[2 * lane + 1];
    float a0 = 0.f, a1 = 0.f, invh;

    if (!fb) {
        float ps0 = p0, ps1 = p1, ps2 = p2, ps3 = p3;
#pragma unroll
        for (int m = 1; m < 64; m <<= 1) {     // 64-lane butterfly
            ps0 += __shfl_xor(ps0, m);
            ps1 += __shfl_xor(ps1, m);
            ps2 += __shfl_xor(ps2, m);
            ps3 += __shfl_xor(ps3, m);
        }
        float den = head == 0 ? ps0 : head == 1 ? ps1 : head == 2 ? ps2 : ps3;
        invh = 1.0f / (den + 1e-16f);

        int tot = deg + 1;
        int i = 0;
        for (; i + 3 < tot; i += 4) {          // 4 row-gathers in flight
            int s0 = s_sh[i], s1 = s_sh[i + 1], s2 = s_sh[i + 2], s3 = s_sh[i + 3];
            float q0 = p_sh[i * 4 + head],       q1 = p_sh[(i + 1) * 4 + head];
            float q2 = p_sh[(i + 2) * 4 + head], q3 = p_sh[(i + 3) * 4 + head];
            unsigned int v0 = *(const unsigned int*)(hbf + (size_t)s0 * 128 + 2 * lane);
            unsigned int v1 = *(const unsigned int*)(hbf + (size_t)s1 * 128 + 2 * lane);
            unsigned int v2 = *(const unsigned int*)(hbf + (size_t)s2 * 128 + 2 * lane);
            unsigned int v3 = *(const unsigned int*)(hbf + (size_t)s3 * 128 + 2 * lane);
            a0 += q0 * b2f((unsigned short)v0) + q1 * b2f((unsigned short)v1)
                + q2 * b2f((unsigned short)v2) + q3 * b2f((unsigned short)v3);
            a1 += q0 * b2f((unsigned short)(v0 >> 16)) + q1 * b2f((unsigned short)(v1 >> 16))
                + q2 * b2f((unsigned short)(v2 >> 16)) + q3 * b2f((unsigned short)(v3 >> 16));
        }
        for (; i < tot; ++i) {
            int s0 = s_sh[i];
            float q0 = p_sh[i * 4 + head];
            unsigned int v0 = *(const unsigned int*)(hbf + (size_t)s0 * 128 + 2 * lane);
            a0 += q0 * b2f((unsigned short)v0);
            a1 += q0 * b2f((unsigned short)(v0 >> 16));
        }
    } else {
        int is64 = flags[0];
        float adh = head == 0 ? adv.x : head == 1 ? adv.y : head == 2 ? adv.z : adv.w;
        float den = 0.f;
        {   // self-loop
            float ev = asf[(size_t)n * 4 + head] + adh; ev = fmaxf(ev, 0.2f * ev);
            float p = __expf(ev);
            unsigned int v = *(const unsigned int*)(hbf + (size_t)n * 128 + 2 * lane);
            den += p;
            a0 += p * b2f((unsigned short)v);
            a1 += p * b2f((unsigned short)(v >> 16));
        }
        for (int e = 0; e < E; ++e) {
            int d = edge_at(idx32, idx64, is64, (long long)E + e);
            if (d == n) {
                int s = edge_at(idx32, idx64, is64, e);
                float ev = asf[(size_t)s * 4 + head] + adh; ev = fmaxf(ev, 0.2f * ev);
                float p = __expf(ev);
                unsigned int v = *(const unsigned int*)(hbf + (size_t)s * 128 + 2 * lane);
                den += p;
                a0 += p * b2f((unsigned short)v);
                a1 += p * b2f((unsigned short)(v >> 16));
            }
        }
        invh = 1.0f / (den + 1e-16f);
    }

    a0 = a0 * invh + b0;
    a1 = a1 * invh + b1;
    if (flags[1]) {
        unsigned int pk = (unsigned int)f2b(a0) | ((unsigned int)f2b(a1) << 16);
        ((unsigned int*)outv)[(size_t)n * 64 + lane] = pk;
    } else {
        float2 f2; f2.x = a0; f2.y = a1;
        *(float2*)((float*)outv + (size_t)n * 128 + 2 * lane) = f2;
    }
}

// ---------------------------------------------------------------------------
extern "C" void kernel_launch(void* const* d_in, const int* in_sizes, int n_in,
                              void* d_out, int out_size, void* d_ws, size_t ws_size,
                              hipStream_t stream) {
    const void*      xv    = d_in[0];
    const int*       idx32 = (const int*)d_in[1];
    const long long* idx64 = (const long long*)d_in[1];

    int N = in_sizes[0] / 128;
    int E = in_sizes[1] / 2;

    char* ws = (char*)d_ws;
    size_t o = 0;
    auto alloc = [&](size_t bytes) {
        size_t r = o; o += (bytes + 255) & ~(size_t)255; return r;
    };
    unsigned short* hbf = (unsigned short*)(ws + alloc((size_t)N * 128 * 2));
    _Float16* Wth = (_Float16*)(ws + alloc(16384 * 2));
    _Float16* Wtl = (_Float16*)(ws + alloc(16384 * 2));
    float* attf  = (float*)(ws + alloc(256 * 4));
    float* biasf = (float*)(ws + alloc(128 * 4));
    float* asf   = (float*)(ws + alloc((size_t)N * 4 * 4));
    float* adf   = (float*)(ws + alloc((size_t)N * 4 * 4));
    int* cnt     = (int*)(ws + alloc((size_t)N * CNTS * 4));
    int* flags   = (int*)(ws + alloc(256));
    int* esrc    = (int*)(ws + alloc((size_t)N * SLOT * 4));
    int NBK = (N + 63) >> 6;
    int* bcnt      = (int*)(ws + alloc((size_t)NBK * 4));
    unsigned* bdat = (unsigned*)(ws + alloc((size_t)NBK * BCAP * 4));

    int Gg = (N + 63) / 64;                  // gemm tiles (64 rows each)
    int SB = (E + KCH - 1) / KCH;            // scatter chunks
    int NB = SB + Gg;

    k_detect<<<1, 256, 0, stream>>>(idx32, (const unsigned int*)xv, flags);
    k_prep<<<16, 256, 0, stream>>>(d_in[2], d_in[3], d_in[4], d_in[5], flags, Wth, Wtl, attf, biasf);
    if (NBK <= MAXB) {
        hipMemsetAsync(bcnt, 0, (size_t)NBK * 4, stream);
        k_gemm_scatter<<<NB, 256, 0, stream>>>(xv, Wth, Wtl, attf, flags, hbf, asf, adf, N,
                                               idx32, idx64, bcnt, bdat, cnt, esrc, E, Gg, SB);
        k_bagg<<<NBK, 256, 0, stream>>>(bdat, bcnt, hbf, asf, adf, idx32, idx64,
                                        biasf, flags, d_out, N, E);
    } else {
        hipMemsetAsync(cnt, 0, (size_t)N * CNTS * 4, stream);
        k_gemm_scatter<<<NB, 256, 0, stream>>>(xv, Wth, Wtl, attf, flags, hbf, asf, adf, N,
                                               idx32, idx64, bcnt, bdat, cnt, esrc, E, Gg, SB);
        k_aggregate<<<(N + 3) / 4, 256, 0, stream>>>(hbf, asf, adf, cnt, esrc, idx32, idx64,
                                                     biasf, flags, d_out, N, E);
    }
}